// Round 1
// baseline (410.625 us; speedup 1.0000x reference)
//
#include <hip/hip_runtime.h>
#include <hip/hip_bf16.h>

#define NPIX (1024 * 1024)
#define NBATCH 16
#define NBINS 8192

// ---------------------------------------------------------------------------
// Kernel 1: per-block LDS histogram of luminance, flushed to private slice of
// d_ws with plain stores (every byte overwritten -> no init needed).
// ---------------------------------------------------------------------------
__global__ void hist_kernel(const float* __restrict__ img,
                            const float* __restrict__ rgb2yuv,
                            unsigned int* __restrict__ block_hist,
                            int subPerBatch) {
    __shared__ unsigned int lh[NBINS];
    for (int i = threadIdx.x; i < NBINS; i += blockDim.x) lh[i] = 0;
    const float c0 = rgb2yuv[0];
    const float c1 = rgb2yuv[1];
    const float c2 = rgb2yuv[2];
    __syncthreads();

    const int b = blockIdx.x / subPerBatch;
    const int s = blockIdx.x % subPerBatch;
    const int pixPerBlock = NPIX / subPerBatch;
    const size_t base = (size_t)b * 3 * NPIX + (size_t)s * pixPerBlock;

    const float4* r4 = (const float4*)(img + base);
    const float4* g4 = (const float4*)(img + base + NPIX);
    const float4* b4 = (const float4*)(img + base + 2 * (size_t)NPIX);
    const int n4 = pixPerBlock / 4;

    const float scale = (float)NBINS;
    for (int i = threadIdx.x; i < n4; i += blockDim.x) {
        float4 R = r4[i];
        float4 G = g4[i];
        float4 B = b4[i];
        float y0 = c0 * R.x + c1 * G.x + c2 * B.x;
        float y1 = c0 * R.y + c1 * G.y + c2 * B.y;
        float y2 = c0 * R.z + c1 * G.z + c2 * B.z;
        float y3 = c0 * R.w + c1 * G.w + c2 * B.w;
        int i0 = min(NBINS - 1, max(0, (int)(y0 * scale)));
        int i1 = min(NBINS - 1, max(0, (int)(y1 * scale)));
        int i2 = min(NBINS - 1, max(0, (int)(y2 * scale)));
        int i3 = min(NBINS - 1, max(0, (int)(y3 * scale)));
        atomicAdd(&lh[i0], 1u);
        atomicAdd(&lh[i1], 1u);
        atomicAdd(&lh[i2], 1u);
        atomicAdd(&lh[i3], 1u);
    }
    __syncthreads();

    unsigned int* dst = block_hist + (size_t)blockIdx.x * NBINS;
    for (int i = threadIdx.x; i < NBINS; i += blockDim.x) dst[i] = lh[i];
}

// ---------------------------------------------------------------------------
// Kernel 2: one block per batch. Reduce sub-histograms, scan, find the 4
// order statistics (10485,10486 for p1; 1038089,1038090 for p99),
// interpolate within bin, write (blkpt, mult) per batch.
// ---------------------------------------------------------------------------
__global__ __launch_bounds__(1024) void scan_kernel(
        const unsigned int* __restrict__ block_hist,
        float* __restrict__ stats, int subPerBatch) {
    __shared__ unsigned int hist[NBINS];
    __shared__ unsigned int segsum[1024];
    __shared__ float vals[4];

    const int b = blockIdx.x;
    const int t = threadIdx.x;

    // Reduce subPerBatch sub-histograms into LDS (coalesced: thread-strided bins)
    for (int i = t; i < NBINS; i += 1024) {
        unsigned int s = 0;
        const unsigned int* p = block_hist + ((size_t)b * subPerBatch) * NBINS + i;
        for (int k = 0; k < subPerBatch; ++k) s += p[(size_t)k * NBINS];
        hist[i] = s;
    }
    __syncthreads();

    // Contiguous 8-bin segment sums
    const int BPT = NBINS / 1024;  // 8
    unsigned int ss = 0;
#pragma unroll
    for (int j = 0; j < BPT; ++j) ss += hist[t * BPT + j];
    segsum[t] = ss;
    __syncthreads();

    // Hillis-Steele inclusive scan over 1024 segment sums
    for (int off = 1; off < 1024; off <<= 1) {
        unsigned int v = segsum[t];
        unsigned int add = (t >= off) ? segsum[t - off] : 0u;
        __syncthreads();
        segsum[t] = v + add;
        __syncthreads();
    }

    const unsigned int cumincl = segsum[t];
    const unsigned int cumbefore = (t > 0) ? segsum[t - 1] : 0u;

    const unsigned int ranks[4] = {10485u, 10486u, 1038089u, 1038090u};
#pragma unroll
    for (int q = 0; q < 4; ++q) {
        unsigned int r = ranks[q];
        if (r >= cumbefore && r < cumincl) {
            unsigned int running = cumbefore;
#pragma unroll
            for (int j = 0; j < BPT; ++j) {
                unsigned int c = hist[t * BPT + j];
                if (r < running + c) {
                    float v = ((float)(t * BPT + j) +
                               ((float)(r - running) + 0.5f) / (float)c) *
                              (1.0f / (float)NBINS);
                    vals[q] = v;
                    break;
                }
                running += c;
            }
        }
    }
    __syncthreads();

    if (t == 0) {
        float blk = 0.25f * vals[0] + 0.75f * vals[1];
        float wht = 0.75f * vals[2] + 0.25f * vals[3];
        float mult = fminf(1.0f / (wht - blk), 1.5f);
        stats[b * 2 + 0] = blk;
        stats[b * 2 + 1] = mult;
    }
}

// ---------------------------------------------------------------------------
// Kernel 3: out = clip((img - blk[b]) * mult[b], 0, 1), float4 streams.
// One block handles 1024 float4s of one batch.
// ---------------------------------------------------------------------------
__global__ void apply_kernel(const float* __restrict__ img,
                             const float* __restrict__ stats,
                             float* __restrict__ out) {
    const int blocksPerBatch = (3 * NPIX / 4) / 1024;  // 768
    const int b = blockIdx.x / blocksPerBatch;
    const int c = blockIdx.x % blocksPerBatch;
    const float blk = stats[b * 2 + 0];
    const float mult = stats[b * 2 + 1];

    const float4* in4 = (const float4*)(img + (size_t)b * 3 * NPIX) + (size_t)c * 1024;
    float4* out4 = (float4*)(out + (size_t)b * 3 * NPIX) + (size_t)c * 1024;

#pragma unroll
    for (int i = 0; i < 4; ++i) {
        int idx = i * 256 + threadIdx.x;
        float4 v = in4[idx];
        v.x = fminf(fmaxf((v.x - blk) * mult, 0.0f), 1.0f);
        v.y = fminf(fmaxf((v.y - blk) * mult, 0.0f), 1.0f);
        v.z = fminf(fmaxf((v.z - blk) * mult, 0.0f), 1.0f);
        v.w = fminf(fmaxf((v.w - blk) * mult, 0.0f), 1.0f);
        out4[idx] = v;
    }
}

extern "C" void kernel_launch(void* const* d_in, const int* in_sizes, int n_in,
                              void* d_out, int out_size, void* d_ws, size_t ws_size,
                              hipStream_t stream) {
    const float* img = (const float*)d_in[0];
    const float* rgb2yuv = (const float*)d_in[1];
    float* out = (float*)d_out;

    // Workspace layout: [0,128): stats (16 * {blk, mult}); [256, ...): block hists
    float* stats = (float*)d_ws;
    unsigned int* block_hist = (unsigned int*)((char*)d_ws + 256);

    // Pick the largest sub-histogram count that fits in the workspace.
    int subPerBatch = 32;
    while (subPerBatch > 1 &&
           256 + (size_t)subPerBatch * NBATCH * NBINS * 4 > ws_size) {
        subPerBatch >>= 1;
    }

    hist_kernel<<<NBATCH * subPerBatch, 256, 0, stream>>>(img, rgb2yuv, block_hist,
                                                          subPerBatch);
    scan_kernel<<<NBATCH, 1024, 0, stream>>>(block_hist, stats, subPerBatch);

    const int applyBlocks = NBATCH * ((3 * NPIX / 4) / 1024);  // 12288
    apply_kernel<<<applyBlocks, 256, 0, stream>>>(img, stats, out);
}

// Round 2
// 383.005 us; speedup vs baseline: 1.0721x; 1.0721x over previous
//
#include <hip/hip_runtime.h>
#include <hip/hip_bf16.h>

#define NPIX (1024 * 1024)
#define NBATCH 16
#define NBINS 8192
#define SUBPB 64  // hist blocks per batch

// ---------------------------------------------------------------------------
// Kernel 0: zero the per-batch global histograms (ws is poisoned each call).
// ---------------------------------------------------------------------------
__global__ void zero_kernel(unsigned int* __restrict__ ghist) {
    int i = blockIdx.x * blockDim.x + threadIdx.x;
    int n = NBATCH * NBINS;
    for (; i < n; i += gridDim.x * blockDim.x) ghist[i] = 0u;
}

// ---------------------------------------------------------------------------
// Kernel 1: per-block LDS histogram of luminance, flushed with global
// atomicAdd into the per-batch histogram (coalesced addresses; <=64-way
// contention per bin across blocks of one batch).
// ---------------------------------------------------------------------------
__global__ __launch_bounds__(256) void hist_kernel(
        const float* __restrict__ img,
        const float* __restrict__ rgb2yuv,
        unsigned int* __restrict__ ghist) {
    __shared__ unsigned int lh[NBINS];
    for (int i = threadIdx.x; i < NBINS; i += blockDim.x) lh[i] = 0;
    const float c0 = rgb2yuv[0];
    const float c1 = rgb2yuv[1];
    const float c2 = rgb2yuv[2];
    __syncthreads();

    const int b = blockIdx.x / SUBPB;
    const int s = blockIdx.x % SUBPB;
    const int pixPerBlock = NPIX / SUBPB;  // 16384
    const size_t base = (size_t)b * 3 * NPIX + (size_t)s * pixPerBlock;

    const float4* r4 = (const float4*)(img + base);
    const float4* g4 = (const float4*)(img + base + NPIX);
    const float4* b4 = (const float4*)(img + base + 2 * (size_t)NPIX);
    const int n4 = pixPerBlock / 4;  // 4096

    const float scale = (float)NBINS;
    for (int i = threadIdx.x; i < n4; i += blockDim.x) {
        float4 R = r4[i];
        float4 G = g4[i];
        float4 B = b4[i];
        float y0 = c0 * R.x + c1 * G.x + c2 * B.x;
        float y1 = c0 * R.y + c1 * G.y + c2 * B.y;
        float y2 = c0 * R.z + c1 * G.z + c2 * B.z;
        float y3 = c0 * R.w + c1 * G.w + c2 * B.w;
        int i0 = min(NBINS - 1, max(0, (int)(y0 * scale)));
        int i1 = min(NBINS - 1, max(0, (int)(y1 * scale)));
        int i2 = min(NBINS - 1, max(0, (int)(y2 * scale)));
        int i3 = min(NBINS - 1, max(0, (int)(y3 * scale)));
        atomicAdd(&lh[i0], 1u);
        atomicAdd(&lh[i1], 1u);
        atomicAdd(&lh[i2], 1u);
        atomicAdd(&lh[i3], 1u);
    }
    __syncthreads();

    unsigned int* dst = ghist + (size_t)b * NBINS;
    for (int i = threadIdx.x; i < NBINS; i += blockDim.x) {
        unsigned int v = lh[i];
        if (v) atomicAdd(&dst[i], v);
    }
}

// ---------------------------------------------------------------------------
// Kernel 2: one block per batch. Load 8192-bin histogram (32 KB), scan,
// locate the 4 order statistics (10485,10486 / 1038089,1038090),
// interpolate within bin, write (blkpt, mult) per batch.
// ---------------------------------------------------------------------------
__global__ __launch_bounds__(1024) void scan_kernel(
        const unsigned int* __restrict__ ghist,
        float* __restrict__ stats) {
    __shared__ unsigned int hist[NBINS];
    __shared__ unsigned int segsum[1024];
    __shared__ float vals[4];

    const int b = blockIdx.x;
    const int t = threadIdx.x;

    for (int i = t; i < NBINS; i += 1024)
        hist[i] = ghist[(size_t)b * NBINS + i];
    __syncthreads();

    // Contiguous 8-bin segment sums
    const int BPT = NBINS / 1024;  // 8
    unsigned int ss = 0;
#pragma unroll
    for (int j = 0; j < BPT; ++j) ss += hist[t * BPT + j];
    segsum[t] = ss;
    __syncthreads();

    // Hillis-Steele inclusive scan over 1024 segment sums
    for (int off = 1; off < 1024; off <<= 1) {
        unsigned int v = segsum[t];
        unsigned int add = (t >= off) ? segsum[t - off] : 0u;
        __syncthreads();
        segsum[t] = v + add;
        __syncthreads();
    }

    const unsigned int cumincl = segsum[t];
    const unsigned int cumbefore = (t > 0) ? segsum[t - 1] : 0u;

    const unsigned int ranks[4] = {10485u, 10486u, 1038089u, 1038090u};
#pragma unroll
    for (int q = 0; q < 4; ++q) {
        unsigned int r = ranks[q];
        if (r >= cumbefore && r < cumincl) {
            unsigned int running = cumbefore;
#pragma unroll
            for (int j = 0; j < BPT; ++j) {
                unsigned int c = hist[t * BPT + j];
                if (r < running + c) {
                    float v = ((float)(t * BPT + j) +
                               ((float)(r - running) + 0.5f) / (float)c) *
                              (1.0f / (float)NBINS);
                    vals[q] = v;
                    break;
                }
                running += c;
            }
        }
    }
    __syncthreads();

    if (t == 0) {
        float blk = 0.25f * vals[0] + 0.75f * vals[1];
        float wht = 0.75f * vals[2] + 0.25f * vals[3];
        float mult = fminf(1.0f / (wht - blk), 1.5f);
        stats[b * 2 + 0] = blk;
        stats[b * 2 + 1] = mult;
    }
}

// ---------------------------------------------------------------------------
// Kernel 3: out = clip((img - blk[b]) * mult[b], 0, 1), float4 streams.
// ---------------------------------------------------------------------------
__global__ __launch_bounds__(256) void apply_kernel(
        const float* __restrict__ img,
        const float* __restrict__ stats,
        float* __restrict__ out) {
    const int blocksPerBatch = (3 * NPIX / 4) / 1024;  // 768
    const int b = blockIdx.x / blocksPerBatch;
    const int c = blockIdx.x % blocksPerBatch;
    const float blk = stats[b * 2 + 0];
    const float mult = stats[b * 2 + 1];

    const float4* in4 = (const float4*)(img + (size_t)b * 3 * NPIX) + (size_t)c * 1024;
    float4* out4 = (float4*)(out + (size_t)b * 3 * NPIX) + (size_t)c * 1024;

#pragma unroll
    for (int i = 0; i < 4; ++i) {
        int idx = i * 256 + threadIdx.x;
        float4 v = in4[idx];
        v.x = fminf(fmaxf((v.x - blk) * mult, 0.0f), 1.0f);
        v.y = fminf(fmaxf((v.y - blk) * mult, 0.0f), 1.0f);
        v.z = fminf(fmaxf((v.z - blk) * mult, 0.0f), 1.0f);
        v.w = fminf(fmaxf((v.w - blk) * mult, 0.0f), 1.0f);
        out4[idx] = v;
    }
}

extern "C" void kernel_launch(void* const* d_in, const int* in_sizes, int n_in,
                              void* d_out, int out_size, void* d_ws, size_t ws_size,
                              hipStream_t stream) {
    const float* img = (const float*)d_in[0];
    const float* rgb2yuv = (const float*)d_in[1];
    float* out = (float*)d_out;

    // Workspace layout: [0,128): stats (16 * {blk, mult}); [256, ...): ghist
    float* stats = (float*)d_ws;
    unsigned int* ghist = (unsigned int*)((char*)d_ws + 256);

    zero_kernel<<<64, 256, 0, stream>>>(ghist);
    hist_kernel<<<NBATCH * SUBPB, 256, 0, stream>>>(img, rgb2yuv, ghist);
    scan_kernel<<<NBATCH, 1024, 0, stream>>>(ghist, stats);

    const int applyBlocks = NBATCH * ((3 * NPIX / 4) / 1024);  // 12288
    apply_kernel<<<applyBlocks, 256, 0, stream>>>(img, stats, out);
}

// Round 4
// 382.106 us; speedup vs baseline: 1.0746x; 1.0024x over previous
//
#include <hip/hip_runtime.h>
#include <hip/hip_bf16.h>

#define NPIX (1024 * 1024)
#define NBATCH 16
#define NBINS 8192
#define SUBPB 64  // hist blocks per batch

typedef float vfloat4 __attribute__((ext_vector_type(4)));

// ---------------------------------------------------------------------------
// Kernel 0: zero the per-batch global histograms (ws is poisoned each call).
// ---------------------------------------------------------------------------
__global__ void zero_kernel(unsigned int* __restrict__ ghist) {
    int i = blockIdx.x * blockDim.x + threadIdx.x;
    int n = NBATCH * NBINS;
    for (; i < n; i += gridDim.x * blockDim.x) ghist[i] = 0u;
}

// ---------------------------------------------------------------------------
// Kernel 1: per-block LDS histogram of luminance, flushed with global
// atomicAdd into the per-batch histogram. Reads ALL of img -> warms the
// 256 MiB Infinity Cache for the apply pass (img = 201 MB fits).
// ---------------------------------------------------------------------------
__global__ __launch_bounds__(256) void hist_kernel(
        const float* __restrict__ img,
        const float* __restrict__ rgb2yuv,
        unsigned int* __restrict__ ghist) {
    __shared__ unsigned int lh[NBINS];
    for (int i = threadIdx.x; i < NBINS; i += blockDim.x) lh[i] = 0;
    const float c0 = rgb2yuv[0];
    const float c1 = rgb2yuv[1];
    const float c2 = rgb2yuv[2];
    __syncthreads();

    const int b = blockIdx.x / SUBPB;
    const int s = blockIdx.x % SUBPB;
    const int pixPerBlock = NPIX / SUBPB;  // 16384
    const size_t base = (size_t)b * 3 * NPIX + (size_t)s * pixPerBlock;

    const float4* r4 = (const float4*)(img + base);
    const float4* g4 = (const float4*)(img + base + NPIX);
    const float4* b4 = (const float4*)(img + base + 2 * (size_t)NPIX);
    const int n4 = pixPerBlock / 4;  // 4096

    const float scale = (float)NBINS;
    for (int i = threadIdx.x; i < n4; i += blockDim.x) {
        float4 R = r4[i];
        float4 G = g4[i];
        float4 B = b4[i];
        float y0 = c0 * R.x + c1 * G.x + c2 * B.x;
        float y1 = c0 * R.y + c1 * G.y + c2 * B.y;
        float y2 = c0 * R.z + c1 * G.z + c2 * B.z;
        float y3 = c0 * R.w + c1 * G.w + c2 * B.w;
        int i0 = min(NBINS - 1, max(0, (int)(y0 * scale)));
        int i1 = min(NBINS - 1, max(0, (int)(y1 * scale)));
        int i2 = min(NBINS - 1, max(0, (int)(y2 * scale)));
        int i3 = min(NBINS - 1, max(0, (int)(y3 * scale)));
        atomicAdd(&lh[i0], 1u);
        atomicAdd(&lh[i1], 1u);
        atomicAdd(&lh[i2], 1u);
        atomicAdd(&lh[i3], 1u);
    }
    __syncthreads();

    unsigned int* dst = ghist + (size_t)b * NBINS;
    for (int i = threadIdx.x; i < NBINS; i += blockDim.x) {
        unsigned int v = lh[i];
        if (v) atomicAdd(&dst[i], v);
    }
}

// ---------------------------------------------------------------------------
// Kernel 2: one block per batch. Load 8192-bin histogram (32 KB), scan,
// locate the 4 order statistics (10485,10486 / 1038089,1038090),
// interpolate within bin, write (blkpt, mult) per batch.
// ---------------------------------------------------------------------------
__global__ __launch_bounds__(1024) void scan_kernel(
        const unsigned int* __restrict__ ghist,
        float* __restrict__ stats) {
    __shared__ unsigned int hist[NBINS];
    __shared__ unsigned int segsum[1024];
    __shared__ float vals[4];

    const int b = blockIdx.x;
    const int t = threadIdx.x;

    for (int i = t; i < NBINS; i += 1024)
        hist[i] = ghist[(size_t)b * NBINS + i];
    __syncthreads();

    // Contiguous 8-bin segment sums
    const int BPT = NBINS / 1024;  // 8
    unsigned int ss = 0;
#pragma unroll
    for (int j = 0; j < BPT; ++j) ss += hist[t * BPT + j];
    segsum[t] = ss;
    __syncthreads();

    // Hillis-Steele inclusive scan over 1024 segment sums
    for (int off = 1; off < 1024; off <<= 1) {
        unsigned int v = segsum[t];
        unsigned int add = (t >= off) ? segsum[t - off] : 0u;
        __syncthreads();
        segsum[t] = v + add;
        __syncthreads();
    }

    const unsigned int cumincl = segsum[t];
    const unsigned int cumbefore = (t > 0) ? segsum[t - 1] : 0u;

    const unsigned int ranks[4] = {10485u, 10486u, 1038089u, 1038090u};
#pragma unroll
    for (int q = 0; q < 4; ++q) {
        unsigned int r = ranks[q];
        if (r >= cumbefore && r < cumincl) {
            unsigned int running = cumbefore;
#pragma unroll
            for (int j = 0; j < BPT; ++j) {
                unsigned int c = hist[t * BPT + j];
                if (r < running + c) {
                    float v = ((float)(t * BPT + j) +
                               ((float)(r - running) + 0.5f) / (float)c) *
                              (1.0f / (float)NBINS);
                    vals[q] = v;
                    break;
                }
                running += c;
            }
        }
    }
    __syncthreads();

    if (t == 0) {
        float blk = 0.25f * vals[0] + 0.75f * vals[1];
        float wht = 0.75f * vals[2] + 0.25f * vals[3];
        float mult = fminf(1.0f / (wht - blk), 1.5f);
        stats[b * 2 + 0] = blk;
        stats[b * 2 + 1] = mult;
    }
}

// ---------------------------------------------------------------------------
// Kernel 3: out = clip((img - blk[b]) * mult[b], 0, 1).
// Reads img (L3-resident after hist); writes out with NON-TEMPORAL stores
// (native clang vector type required by the builtin) so the write stream
// does not evict img from the Infinity Cache.
// ---------------------------------------------------------------------------
__global__ __launch_bounds__(256) void apply_kernel(
        const float* __restrict__ img,
        const float* __restrict__ stats,
        float* __restrict__ out) {
    const int blocksPerBatch = (3 * NPIX / 4) / 1024;  // 768
    const int b = blockIdx.x / blocksPerBatch;
    const int c = blockIdx.x % blocksPerBatch;
    const float blk = stats[b * 2 + 0];
    const float mult = stats[b * 2 + 1];

    const vfloat4* in4 =
        (const vfloat4*)(img + (size_t)b * 3 * NPIX) + (size_t)c * 1024;
    vfloat4* out4 = (vfloat4*)(out + (size_t)b * 3 * NPIX) + (size_t)c * 1024;

#pragma unroll
    for (int i = 0; i < 4; ++i) {
        int idx = i * 256 + threadIdx.x;
        vfloat4 v = in4[idx];
        v.x = fminf(fmaxf((v.x - blk) * mult, 0.0f), 1.0f);
        v.y = fminf(fmaxf((v.y - blk) * mult, 0.0f), 1.0f);
        v.z = fminf(fmaxf((v.z - blk) * mult, 0.0f), 1.0f);
        v.w = fminf(fmaxf((v.w - blk) * mult, 0.0f), 1.0f);
        __builtin_nontemporal_store(v, out4 + idx);
    }
}

extern "C" void kernel_launch(void* const* d_in, const int* in_sizes, int n_in,
                              void* d_out, int out_size, void* d_ws, size_t ws_size,
                              hipStream_t stream) {
    const float* img = (const float*)d_in[0];
    const float* rgb2yuv = (const float*)d_in[1];
    float* out = (float*)d_out;

    // Workspace layout: [0,128): stats (16 * {blk, mult}); [256, ...): ghist
    float* stats = (float*)d_ws;
    unsigned int* ghist = (unsigned int*)((char*)d_ws + 256);

    zero_kernel<<<256, 256, 0, stream>>>(ghist);
    hist_kernel<<<NBATCH * SUBPB, 256, 0, stream>>>(img, rgb2yuv, ghist);
    scan_kernel<<<NBATCH, 1024, 0, stream>>>(ghist, stats);

    const int applyBlocks = NBATCH * ((3 * NPIX / 4) / 1024);  // 12288
    apply_kernel<<<applyBlocks, 256, 0, stream>>>(img, stats, out);
}